// Round 7
// baseline (71.466 us; speedup 1.0000x reference)
//
#include <hip/hip_runtime.h>

// SubTokenEmbedding: fused embedding gather + sorted-segment sum pooling.
//
// out[s, :] = sum_{i : segs[i]==s} table[ids[i], :]     (segs sorted ascending)
//
// Per launch (all on `stream`, deterministic):
//   1) prep_kernel (fused):
//        a) convert f32 table -> bf16, COLUMN-SPLIT into two half-tables in
//           d_ws: ctabA = cols [0,64) (128 B/row, 4.1 MB), ctabB = cols
//           [64,128). Each half FITS a 4 MiB per-XCD L2.
//        b) starts[s] = lower_bound(segs, s) via scatter from adjacent diffs
//   2) main kernel launched TWICE sequentially (pass A: cols 0-63 from ctabA,
//      pass B: cols 64-127 from ctabB). Per pass the random-gather working
//      set is 4.1 MB -> ~all-L2-hit after warmup, so HBM sees only the
//      streaming traffic (~63 MB/pass) instead of ~130 MB of random 256 B
//      fetches. One 32-lane group per SPG consecutive segments; lane l holds
//      uint #l (2 bf16) of the 128 B half-row -> one coalesced load per row,
//      UNROLL rows in flight. Output stores and seg/id loads are
//      non-temporal so they don't evict the half-table from L2.
//
// No atomics; every output element written exactly once per launch (disjoint
// column halves across the two passes), so the poisoned d_out needs no
// pre-zeroing.

#define H_EMB   128
#define LPG     32      // lanes per group; 32 x uint = 128 B half-row
#define SPG     8       // segments per group
#define UNROLL  8       // half-row loads kept in flight per group
#define HROW_U  32      // uints per half-row

__device__ __forceinline__ unsigned f2bf_rne(float f) {
    unsigned u = __float_as_uint(f);
    return (u + 0x7FFFu + ((u >> 16) & 1u)) >> 16;   // round-to-nearest-even
}

__device__ __forceinline__ void nt_store2(float* p, float x, float y) {
    unsigned long long v = (unsigned long long)__float_as_uint(x)
                         | ((unsigned long long)__float_as_uint(y) << 32);
    __builtin_nontemporal_store(v, (unsigned long long*)p);
}

__global__ __launch_bounds__(256)
void prep_kernel(const float* __restrict__ t, unsigned* __restrict__ ctabA,
                 int n_pairs, int vocab,
                 const int* __restrict__ segs, int* __restrict__ starts,
                 int n, int n_nodes)
{
    const int i = blockIdx.x * blockDim.x + threadIdx.x;
    if (i < n_pairs) {
        // pair i covers f32 cols (2c, 2c+1) of row r
        const int r = i >> 6;          // H_EMB/2 = 64 pairs per row
        const int c = i & 63;
        unsigned long long w =
            __builtin_nontemporal_load((const unsigned long long*)t + i);
        const float fx = __uint_as_float((unsigned)w);
        const float fy = __uint_as_float((unsigned)(w >> 32));
        const unsigned packed = f2bf_rne(fx) | (f2bf_rne(fy) << 16);
        unsigned* dst = (c < 32)
            ? ctabA + (size_t)r * HROW_U + c                          // half A
            : ctabA + (size_t)vocab * HROW_U + (size_t)r * HROW_U + (c - 32); // half B
        *dst = packed;
    }
    if (i < n) {
        const int s  = __builtin_nontemporal_load(segs + i);
        const int sp = (i == 0) ? -1 : __builtin_nontemporal_load(segs + i - 1);
        for (int seg = sp + 1; seg <= s; ++seg) starts[seg] = i;   // run-starts + gaps
        if (i == n - 1)
            for (int seg = s + 1; seg <= n_nodes; ++seg) starts[seg] = n;
    }
}

// -------- half-table main kernel: one 32-lane group per SPG segments --------
__global__ __launch_bounds__(256)
void SubTokenEmbedding_6734508720780_kernel(
    const unsigned* __restrict__ ctabH,  // bf16 half-table, HROW_U uint/row
    const int*      __restrict__ ids,
    const int*      __restrict__ segs,
    const int*      __restrict__ starts, // [n_nodes+1]
    float*          __restrict__ out,    // already offset to this column half
    int n_nodes)
{
    const int group = (int)((blockIdx.x * blockDim.x + threadIdx.x) / LPG);
    const int lane  = (int)(threadIdx.x & (LPG - 1));
    const int s0    = group * SPG;
    if (s0 >= n_nodes) return;
    const int s_end = min(s0 + SPG, n_nodes);

    const int beg = starts[s0];
    const int end = starts[s_end];

    const unsigned* trow = ctabH + lane;         // lane l reads uint #l of half-row
    float*          orow = out  + lane * 2;      // lane l owns 2 floats of the half

    float accx = 0.f, accy = 0.f;
    int cur = s0;

    // seg/id stream: read-once, non-temporal, coalesced 128 B per group
    int sv = 0, iv = 0;
    if (beg + lane < end) {
        sv = __builtin_nontemporal_load(segs + beg + lane);
        iv = __builtin_nontemporal_load(ids  + beg + lane);
    }

    for (int base = beg; base < end; base += LPG) {
        const int cnt = min(LPG, end - base);
        const int nb  = base + LPG;
        int sv2 = 0, iv2 = 0;
        if (nb + lane < end) {
            sv2 = __builtin_nontemporal_load(segs + nb + lane);
            iv2 = __builtin_nontemporal_load(ids  + nb + lane);
        }

        for (int k = 0; k < cnt; k += UNROLL) {
            int s_a[UNROLL], id_a[UNROLL];
            #pragma unroll
            for (int u = 0; u < UNROLL; ++u) {
                s_a[u]  = __shfl(sv, k + u, LPG);
                id_a[u] = __shfl(iv, k + u, LPG);
            }
            // issue all gathers before consuming any (OOR u reads row 0: harmless)
            unsigned tv[UNROLL];
            #pragma unroll
            for (int u = 0; u < UNROLL; ++u)
                tv[u] = trow[(size_t)id_a[u] * HROW_U];   // cached: the reused data

            #pragma unroll
            for (int u = 0; u < UNROLL; ++u) {
                if (k + u < cnt) {
                    const int s = s_a[u];
                    if (s != cur) {
                        nt_store2(orow + (size_t)cur * H_EMB, accx, accy);
                        accx = 0.f; accy = 0.f;
                        for (int z = cur + 1; z < s; ++z)
                            nt_store2(orow + (size_t)z * H_EMB, 0.f, 0.f);
                        cur = s;
                    }
                    accx += __uint_as_float(tv[u] << 16);
                    accy += __uint_as_float(tv[u] & 0xFFFF0000u);
                }
            }
        }
        sv = sv2; iv = iv2;
    }

    // final flush: cur, then zeros through s_end-1
    nt_store2(orow + (size_t)cur * H_EMB, accx, accy);
    for (int z = cur + 1; z < s_end; ++z)
        nt_store2(orow + (size_t)z * H_EMB, 0.f, 0.f);
}

// -------- f32 fallback (ws too small for split table / starts) --------
__global__ __launch_bounds__(256)
void subtok_f32_kernel(
    const float* __restrict__ table,
    const int*   __restrict__ ids,
    const int*   __restrict__ segs,
    float*       __restrict__ out,
    int total_subtokens, int n_nodes)
{
    const int group = (int)((blockIdx.x * blockDim.x + threadIdx.x) / 32);
    const int lane  = (int)(threadIdx.x & 31);
    const int s0    = group * SPG;
    if (s0 >= n_nodes) return;
    const int s_end = min(s0 + SPG, n_nodes);

    auto lower_bound = [&](int v) -> int {
        int lo = 0, hi = total_subtokens;
        while (lo < hi) { int m = (lo + hi) >> 1; if (segs[m] < v) lo = m + 1; else hi = m; }
        return lo;
    };
    const int beg = lower_bound(s0);
    const int end = lower_bound(s_end);

    const float* trow = table + (size_t)lane * 4;
    float*       orow = out   + (size_t)lane * 4;
    float4 acc = make_float4(0.f, 0.f, 0.f, 0.f);
    int cur = s0;

    for (int j = beg; j < end; ++j) {
        const int s  = segs[j];
        const int id = ids[j];
        if (s != cur) {
            *reinterpret_cast<float4*>(orow + (size_t)cur * H_EMB) = acc;
            const float4 zero = make_float4(0.f, 0.f, 0.f, 0.f);
            for (int z = cur + 1; z < s; ++z)
                *reinterpret_cast<float4*>(orow + (size_t)z * H_EMB) = zero;
            acc = zero; cur = s;
        }
        const float4 t = *reinterpret_cast<const float4*>(trow + (size_t)id * H_EMB);
        acc.x += t.x; acc.y += t.y; acc.z += t.z; acc.w += t.w;
    }
    *reinterpret_cast<float4*>(orow + (size_t)cur * H_EMB) = acc;
    const float4 zero = make_float4(0.f, 0.f, 0.f, 0.f);
    for (int z = cur + 1; z < s_end; ++z)
        *reinterpret_cast<float4*>(orow + (size_t)z * H_EMB) = zero;
}

extern "C" void kernel_launch(void* const* d_in, const int* in_sizes, int n_in,
                              void* d_out, int out_size, void* d_ws, size_t ws_size,
                              hipStream_t stream) {
    const float* table = (const float*)d_in[0];
    const int*   ids   = (const int*)d_in[1];
    const int*   segs  = (const int*)d_in[2];
    float*       out   = (float*)d_out;

    const int total_subtokens = in_sizes[1];
    const int vocab           = in_sizes[0] / H_EMB;
    const int n_nodes         = out_size / H_EMB;    // out is [n_nodes, 128]

    const size_t starts_bytes = ((size_t)(n_nodes + 1) * sizeof(int) + 15) & ~(size_t)15;
    const size_t ctab_bytes   = 2 * (size_t)vocab * HROW_U * sizeof(unsigned); // both halves
    const int    n_pairs      = vocab * (H_EMB / 2);

    if (ws_size >= starts_bytes + ctab_bytes) {
        int*      starts = (int*)d_ws;
        unsigned* ctabA  = (unsigned*)((char*)d_ws + starts_bytes);
        unsigned* ctabB  = ctabA + (size_t)vocab * HROW_U;

        const int prep_n = max(n_pairs, total_subtokens);
        prep_kernel<<<(prep_n + 255) / 256, 256, 0, stream>>>(
            table, ctabA, n_pairs, vocab, segs, starts, total_subtokens, n_nodes);

        const int n_groups         = (n_nodes + SPG - 1) / SPG;
        const int groups_per_block = 256 / LPG;          // 8
        const int n_blocks         = (n_groups + groups_per_block - 1) / groups_per_block;

        // pass A: columns [0,64)
        SubTokenEmbedding_6734508720780_kernel<<<n_blocks, 256, 0, stream>>>(
            ctabA, ids, segs, starts, out, n_nodes);
        // pass B: columns [64,128)
        SubTokenEmbedding_6734508720780_kernel<<<n_blocks, 256, 0, stream>>>(
            ctabB, ids, segs, starts, out + 64, n_nodes);
    } else {
        const int n_groups = (n_nodes + SPG - 1) / SPG;
        const int n_blocks = (n_groups + 7) / 8;
        subtok_f32_kernel<<<n_blocks, 256, 0, stream>>>(
            table, ids, segs, out, total_subtokens, n_nodes);
    }
}